// Round 6
// baseline (211.969 us; speedup 1.0000x reference)
//
#include <hip/hip_runtime.h>
#include <hip/hip_bf16.h>

typedef __hip_bfloat16 bf16;
typedef __attribute__((ext_vector_type(8))) short short8;
typedef __attribute__((ext_vector_type(4))) float floatx4;

#define B_   4
#define C_   256
#define CQ_  32
#define MID_ 16
#define HW_  3136

__device__ __forceinline__ unsigned short f2bf(float f) {
    __hip_bfloat16 h = __float2bfloat16(f);
    return *(unsigned short*)&h;
}
__device__ __forceinline__ float bf2f(short s) {
    return __uint_as_float(((unsigned)(unsigned short)s) << 16);
}

// ================= K1: kq GEMM (392 blocks) + wfp permute (16) + gpk (1) =================
// kq: per batch GEMM M=64(k|q) x K=256 x N=32px, weights converted fp32->bf16 in-register.
// km/qm written as bf16. wfp[ch][kk], kk=cq*8+m <- w_f[ch][m*32+cq]. gpkb bf16.
__global__ void __launch_bounds__(256) k1_kernel(const float* __restrict__ x,
        const float* __restrict__ w_k, const float* __restrict__ b_k,
        const float* __restrict__ w_q, const float* __restrict__ b_q,
        const float* __restrict__ w_f,
        const float* __restrict__ wg1, const float* __restrict__ bg1,
        const float* __restrict__ wg2, const float* __restrict__ bg2,
        short* __restrict__ km, short* __restrict__ qm,
        short* __restrict__ wfp, short* __restrict__ gpkb) {
    int bid = blockIdx.x, t = threadIdx.x;
    if (bid >= 392) {
        if (bid < 408) {           // wfp: 16 blocks x 4096 elems
            int base = (bid - 392) * 4096;
            #pragma unroll
            for (int s = 0; s < 16; s++) {
                int j = base + s * 256 + t;
                int ch = j >> 8, kk = j & 255;
                wfp[j] = (short)f2bf(w_f[ch * 256 + (kk & 7) * 32 + (kk >> 3)]);
            }
        } else {                   // gpk: 1 block, 1568 entries
            for (int idx = t; idx < CQ_ * 49; idx += 256) {
                int cq = idx / 49, ij = idx % 49;
                int i = ij / 7, j = ij % 7;
                float xp = (float)(j - 3), yp = (float)(3 - i);
                float acc = bg2[cq];
                #pragma unroll
                for (int o = 0; o < MID_; o++) {
                    float g1 = wg1[o * 2] * xp + wg1[o * 2 + 1] * yp + bg1[o];
                    acc += wg2[cq * MID_ + o] * fmaxf(g1, 0.f);
                }
                gpkb[idx] = (short)f2bf(acc);
            }
        }
        return;
    }
    // ---- kq GEMM ----
    __shared__ short lt[32 * 264];   // x-tile [px][c], swizzled 16B chunks
    int hw0 = (bid % 98) * 32;
    int b   = bid / 98;
    {
        int pq = t & 7, cb = t >> 3;
        const float* xb = x + (size_t)b * C_ * HW_ + hw0 + pq * 4;
        #pragma unroll
        for (int ii = 0; ii < 4; ii++) {
            int c = ii * 64 + cb * 2;
            floatx4 fa = *(const floatx4*)(xb + (size_t)c * HW_);
            floatx4 fb = *(const floatx4*)(xb + (size_t)(c + 1) * HW_);
            int c8 = c >> 3, sub = c & 7;
            #pragma unroll
            for (int u = 0; u < 4; u++) {
                int px = pq * 4 + u;
                unsigned uu = (unsigned)f2bf(fa[u]) | ((unsigned)f2bf(fb[u]) << 16);
                *(unsigned*)&lt[px * 264 + ((c8 + (px >> 2)) & 31) * 8 + sub] = uu;
            }
        }
    }
    __syncthreads();

    int wave = t >> 6, lane = t & 63, quad = lane >> 4, nl = lane & 15;
    int m0 = wave * 16;
    int row = m0 + nl;
    const float* wsrc = (row < 32) ? (w_k + row * C_) : (w_q + (row - 32) * C_);

    short8 af[8];
    #pragma unroll
    for (int k0 = 0; k0 < 8; k0++) {
        floatx4 fa = *(const floatx4*)(wsrc + quad * 8 + k0 * 32);
        floatx4 fb = *(const floatx4*)(wsrc + quad * 8 + k0 * 32 + 4);
        short8 v;
        #pragma unroll
        for (int u = 0; u < 4; u++) { v[u] = (short)f2bf(fa[u]); v[u + 4] = (short)f2bf(fb[u]); }
        af[k0] = v;
    }

    floatx4 acc0 = {0.f,0.f,0.f,0.f}, acc1 = {0.f,0.f,0.f,0.f};
    #pragma unroll
    for (int nt = 0; nt < 2; nt++) {
        int px = nt * 16 + nl;
        int prow = px * 264, sw = px >> 2;
        #pragma unroll
        for (int k0 = 0; k0 < 8; k0++) {
            short8 bf = *(const short8*)&lt[prow + (((k0 * 4 + quad) + sw) & 31) * 8];
            if (nt == 0) acc0 = __builtin_amdgcn_mfma_f32_16x16x32_bf16(af[k0], bf, acc0, 0, 0, 0);
            else         acc1 = __builtin_amdgcn_mfma_f32_16x16x32_bf16(af[k0], bf, acc1, 0, 0, 0);
        }
    }

    #pragma unroll
    for (int r = 0; r < 4; r++) {
        int ch = m0 + quad * 4 + r;
        bool isK = (ch < 32);
        int c = isK ? ch : ch - 32;
        float bias = isK ? b_k[c] : b_q[c];
        short* dst = (isK ? km : qm) + ((size_t)b * CQ_ + c) * HW_ + hw0 + nl;
        dst[0]  = (short)f2bf(acc0[r] + bias);
        dst[16] = (short)f2bf(acc1[r] + bias);
    }
}

// ================= K2: fused core (softmax+aggregate) + final conv MFMA =================
// grid (56 rows, 4 batches), 256 threads. LDS union:
//   core phase:  kms[32][448] bf16 | xs[4][436][8] bf16 | gpks[1568] bf16  = 59.7 KB
//   conv phase:  pre[64][264] bf16 (aliases start of buffer)               = 33.8 KB
__global__ void __launch_bounds__(256) k2_fused(const float* __restrict__ x,
        const short* __restrict__ km, const short* __restrict__ qm,
        const short* __restrict__ gpkb, const short* __restrict__ wfp,
        const float* __restrict__ b_f, float* __restrict__ out) {
    __shared__ short lds[29856];
    short* kms  = lds;                   // 32*448 = 14336
    short* xs   = lds + 14336;           // 4*436*8 = 13952
    short* gpks = lds + 14336 + 13952;   // 1568
    short* pre  = lds;                   // alias (conv phase), 64*264 = 16896

    int h = blockIdx.x, b = blockIdx.y, t = threadIdx.x;

    for (int i = t; i < 1568; i += 256) gpks[i] = gpkb[i];
    const short* kmg = km + (size_t)b * CQ_ * HW_;
    for (int u = t; u < 32 * 434; u += 256) {
        int cq = u / 434, px = u % 434;
        int i = px / 62, cc = px % 62;
        int gh = h + i - 3, gw = cc - 3;
        short v = 0;
        if ((unsigned)gh < 56u && (unsigned)gw < 56u) v = kmg[cq * HW_ + gh * 56 + gw];
        kms[cq * 448 + px] = v;
    }
    __syncthreads();

    int cqq = t / 56, w = t % 56;
    bool active = (t < 224);
    float preacc[8][8];
    #pragma unroll
    for (int it = 0; it < 8; it++)
        #pragma unroll
        for (int m = 0; m < 8; m++) preacc[it][m] = 0.f;

    #pragma unroll
    for (int iter = 0; iter < 8; iter++) {
        __syncthreads();   // previous compute done before xs overwrite
        // stage x for cq-group [iter*4 .. iter*4+3] as bf16 [cqi][px'][m]
        for (int u = t; u < 3472; u += 256) {
            int px = u % 434, rest = u / 434;
            int cqi = rest >> 1, mg = rest & 1;
            int cq = iter * 4 + cqi;
            int i = px / 62, cc = px % 62;
            int gh = h + i - 3, gw = cc - 3;
            unsigned lo = 0, hi = 0;
            if ((unsigned)gh < 56u && (unsigned)gw < 56u) {
                const float* xb = x + ((size_t)b * C_ + (mg * 4) * 32 + cq) * HW_ + gh * 56 + gw;
                lo = (unsigned)f2bf(xb[0])              | ((unsigned)f2bf(xb[32 * HW_]) << 16);
                hi = (unsigned)f2bf(xb[(size_t)64*HW_]) | ((unsigned)f2bf(xb[(size_t)96*HW_]) << 16);
            }
            unsigned long long pk = (unsigned long long)lo | ((unsigned long long)hi << 32);
            *(unsigned long long*)&xs[(cqi * 436 + px) * 8 + mg * 4] = pk;
        }
        __syncthreads();
        if (active) {
            int cq = iter * 4 + cqq;
            float q = bf2f(qm[((size_t)b * CQ_ + cq) * HW_ + h * 56 + w]);
            const short* kr = kms + cq * 448;
            const short* gr = gpks + cq * 49;
            const short* xr = xs + cqq * 436 * 8;
            #pragma unroll
            for (int i = 0; i < 7; i++) {
                float v[7], s = 0.f;
                int base = i * 62 + w;
                #pragma unroll
                for (int j = 0; j < 7; j++) {     // logits bounded: exp safe without max-sub
                    v[j] = __expf(bf2f(kr[base + j]) * q + bf2f(gr[i * 7 + j]));
                    s += v[j];
                }
                float inv = 1.0f / s;
                #pragma unroll
                for (int j = 0; j < 7; j++) {
                    float c = v[j] * inv;
                    short8 xv = *(const short8*)&xr[(base + j) * 8];
                    #pragma unroll
                    for (int m = 0; m < 8; m++)
                        preacc[iter][m] += c * bf2f(xv[m]);
                }
            }
        }
    }
    __syncthreads();
    // write pre[px][kk], kk = cq*8+m; zero pad rows 56..63
    if (active) {
        #pragma unroll
        for (int iter = 0; iter < 8; iter++) {
            int cq = iter * 4 + cqq;
            short8 o;
            #pragma unroll
            for (int m = 0; m < 8; m++) o[m] = (short)f2bf(preacc[iter][m]);
            *(short8*)&pre[w * 264 + cq * 8] = o;
        }
    }
    for (int u = t; u < 8 * 264; u += 256) pre[56 * 264 + u] = 0;
    __syncthreads();

    // ---- final conv: out[ch][56px] = wfp[ch][:] @ pre[:,:]^T, M=256 N=56(pad64) K=256 ----
    int wave = t >> 6, lane = t & 63, quad = lane >> 4, nl = lane & 15;
    #pragma unroll
    for (int mt = 0; mt < 4; mt++) {
        int m0 = wave * 64 + mt * 16;
        const short* arow = wfp + (m0 + nl) * C_ + quad * 8;
        short8 af[8];
        #pragma unroll
        for (int k0 = 0; k0 < 8; k0++) af[k0] = *(const short8*)(arow + k0 * 32);
        floatx4 acc[4];
        #pragma unroll
        for (int nt = 0; nt < 4; nt++) acc[nt] = (floatx4){0.f,0.f,0.f,0.f};
        #pragma unroll
        for (int k0 = 0; k0 < 8; k0++) {
            #pragma unroll
            for (int nt = 0; nt < 4; nt++) {
                short8 bf = *(const short8*)&pre[(nt * 16 + nl) * 264 + k0 * 32 + quad * 8];
                acc[nt] = __builtin_amdgcn_mfma_f32_16x16x32_bf16(af[k0], bf, acc[nt], 0, 0, 0);
            }
        }
        #pragma unroll
        for (int r = 0; r < 4; r++) {
            int ch = m0 + quad * 4 + r;
            float bias = b_f[ch];
            float* dst = out + ((size_t)b * C_ + ch) * HW_ + h * 56;
            #pragma unroll
            for (int nt = 0; nt < 4; nt++) {
                int col = nt * 16 + nl;
                if (col < 56) dst[col] = acc[nt][r] + bias;
            }
        }
    }
}

extern "C" void kernel_launch(void* const* d_in, const int* in_sizes, int n_in,
                              void* d_out, int out_size, void* d_ws, size_t ws_size,
                              hipStream_t stream) {
    const float* x    = (const float*)d_in[0];
    const float* w_k  = (const float*)d_in[1];
    const float* b_k  = (const float*)d_in[2];
    const float* w_q  = (const float*)d_in[3];
    const float* b_q  = (const float*)d_in[4];
    const float* w_g1 = (const float*)d_in[5];
    const float* b_g1 = (const float*)d_in[6];
    const float* w_g2 = (const float*)d_in[7];
    const float* b_g2 = (const float*)d_in[8];
    const float* w_f  = (const float*)d_in[9];
    const float* b_f  = (const float*)d_in[10];
    float* out = (float*)d_out;

    short* ws   = (short*)d_ws;
    short* km   = ws;                               // B*CQ*HW bf16
    short* qm   = km + (size_t)B_ * CQ_ * HW_;      // B*CQ*HW bf16
    short* wfp  = qm + (size_t)B_ * CQ_ * HW_;      // 256*256 bf16 (kk-permuted w_f)
    short* gpkb = wfp + C_ * C_;                    // 1568 bf16

    k1_kernel<<<dim3(409), 256, 0, stream>>>(x, w_k, b_k, w_q, b_q, w_f,
                                             w_g1, b_g1, w_g2, b_g2, km, qm, wfp, gpkb);
    k2_fused<<<dim3(56, B_), 256, 0, stream>>>(x, km, qm, gpkb, wfp, b_f, out);
}

// Round 7
// 148.038 us; speedup vs baseline: 1.4319x; 1.4319x over previous
//
#include <hip/hip_runtime.h>
#include <hip/hip_bf16.h>

typedef __hip_bfloat16 bf16;
typedef __attribute__((ext_vector_type(8))) short short8;
typedef __attribute__((ext_vector_type(4))) float floatx4;

#define B_   4
#define C_   256
#define CQ_  32
#define MID_ 16
#define HW_  3136

__device__ __forceinline__ unsigned short f2bf(float f) {
    __hip_bfloat16 h = __float2bfloat16(f);
    return *(unsigned short*)&h;
}
__device__ __forceinline__ float bf2f(short s) {
    return __uint_as_float(((unsigned)(unsigned short)s) << 16);
}

// ============ K1: kq GEMM (blocks 0-391) + wfp permute (392-407) + gpk (408) ============
__global__ void __launch_bounds__(256) kq_setup(const float* __restrict__ x,
        const float* __restrict__ w_k, const float* __restrict__ b_k,
        const float* __restrict__ w_q, const float* __restrict__ b_q,
        const float* __restrict__ w_f,
        const float* __restrict__ wg1, const float* __restrict__ bg1,
        const float* __restrict__ wg2, const float* __restrict__ bg2,
        float* __restrict__ km, float* __restrict__ qm,
        short* __restrict__ wfp, float* __restrict__ gpk) {
    int bid = blockIdx.x, t = threadIdx.x;
    if (bid >= 392) {
        if (bid < 408) {           // wfp[ch][kk], kk=cq*8+m <- w_f[ch][m*32+cq]
            int base = (bid - 392) * 4096;
            #pragma unroll
            for (int s = 0; s < 16; s++) {
                int j = base + s * 256 + t;
                wfp[j] = (short)f2bf(w_f[(j >> 8) * 256 + (j & 7) * 32 + ((j & 255) >> 3)]);
            }
        } else {                   // geometry prior, fp32
            for (int idx = t; idx < CQ_ * 49; idx += 256) {
                int cq = idx / 49, ij = idx % 49;
                int i = ij / 7, j = ij % 7;
                float xp = (float)(j - 3), yp = (float)(3 - i);
                float acc = bg2[cq];
                #pragma unroll
                for (int o = 0; o < MID_; o++) {
                    float g1 = wg1[o * 2] * xp + wg1[o * 2 + 1] * yp + bg1[o];
                    acc += wg2[cq * MID_ + o] * fmaxf(g1, 0.f);
                }
                gpk[idx] = acc;
            }
        }
        return;
    }
    // ---- kq GEMM: M=64 (32 km + 32 qm), K=256, N=32 px ----
    __shared__ short lt[32 * 264];   // [px][c] bf16, 16B chunks swizzled
    int hw0 = (bid % 98) * 32;
    int b   = bid / 98;

    int pq = t & 7, cb = t >> 3;
    const float* xb = x + (size_t)b * C_ * HW_ + hw0 + pq * 4;
    // hoist ALL staging loads (8 float4) before any convert/LDS write
    floatx4 fa[4], fb[4];
    #pragma unroll
    for (int ii = 0; ii < 4; ii++) {
        int c = ii * 64 + cb * 2;
        fa[ii] = *(const floatx4*)(xb + (size_t)c * HW_);
        fb[ii] = *(const floatx4*)(xb + (size_t)(c + 1) * HW_);
    }
    #pragma unroll
    for (int ii = 0; ii < 4; ii++) {
        int c = ii * 64 + cb * 2;
        int c8 = c >> 3, sub = c & 7;
        #pragma unroll
        for (int u = 0; u < 4; u++) {
            int px = pq * 4 + u;
            unsigned uu = (unsigned)f2bf(fa[ii][u]) | ((unsigned)f2bf(fb[ii][u]) << 16);
            *(unsigned*)&lt[px * 264 + ((c8 + (px >> 2)) & 31) * 8 + sub] = uu;
        }
    }

    // A-frags: convert this lane's weight row fp32->bf16 (overlaps barrier wait)
    int wave = t >> 6, lane = t & 63, quad = lane >> 4, nl = lane & 15;
    int m0 = wave * 16;
    int row = m0 + nl;
    const float* wsrc = (row < 32) ? (w_k + row * C_) : (w_q + (row - 32) * C_);
    short8 af[8];
    #pragma unroll
    for (int k0 = 0; k0 < 8; k0++) {
        floatx4 wa = *(const floatx4*)(wsrc + k0 * 32 + quad * 8);
        floatx4 wb = *(const floatx4*)(wsrc + k0 * 32 + quad * 8 + 4);
        short8 v;
        #pragma unroll
        for (int u = 0; u < 4; u++) { v[u] = (short)f2bf(wa[u]); v[u + 4] = (short)f2bf(wb[u]); }
        af[k0] = v;
    }
    __syncthreads();

    floatx4 acc0 = {0.f,0.f,0.f,0.f}, acc1 = {0.f,0.f,0.f,0.f};
    #pragma unroll
    for (int nt = 0; nt < 2; nt++) {
        int px = nt * 16 + nl;
        int prow = px * 264, sw = px >> 2;
        #pragma unroll
        for (int k0 = 0; k0 < 8; k0++) {
            short8 bfr = *(const short8*)&lt[prow + (((k0 * 4 + quad) + sw) & 31) * 8];
            if (nt == 0) acc0 = __builtin_amdgcn_mfma_f32_16x16x32_bf16(af[k0], bfr, acc0, 0, 0, 0);
            else         acc1 = __builtin_amdgcn_mfma_f32_16x16x32_bf16(af[k0], bfr, acc1, 0, 0, 0);
        }
    }
    #pragma unroll
    for (int r = 0; r < 4; r++) {
        int ch = m0 + quad * 4 + r;
        bool isK = (ch < 32);
        int c = isK ? ch : ch - 32;
        float bias = isK ? b_k[c] : b_q[c];
        float* dst = (isK ? km : qm) + ((size_t)b * CQ_ + c) * HW_ + hw0 + nl;
        dst[0]  = acc0[r] + bias;
        dst[16] = acc1[r] + bias;
    }
}

// ============ K2: core V2 — branch-free coalesced staging, bf16 [pos][8m] LDS ============
// grid (7 stripes, 32 cq, 4 b), 448 thr = 8 rows x 56 cols.
// pos p = gw+4 in [1,62]; p in {1,2,3,60,61,62} is ALWAYS outside the image -> constant 0.
__global__ void __launch_bounds__(448) core_kernel(const float* __restrict__ x,
        const float* __restrict__ km, const float* __restrict__ qm,
        const float* __restrict__ gpk, short* __restrict__ pret) {
    __shared__ float kms[14 * 64];     // [rr][p] fp32
    __shared__ short xs[14 * 64 * 8];  // [rr][p][m] bf16

    int ht = blockIdx.x, cq = blockIdx.y, b = blockIdx.z;
    int h0 = ht * 8, t = threadIdx.x;

    const float* kmc = km + ((size_t)b * CQ_ + cq) * HW_;
    // km interior: 196 tasks (rr, s) -> float4 at cols 4s..4s+3 (p = 4+4s)
    if (t < 196) {
        int rr = t / 14, s = t % 14;
        int gh = h0 + rr - 3;
        floatx4 v = {0.f,0.f,0.f,0.f};
        if ((unsigned)gh < 56u) v = *(const floatx4*)&kmc[gh * 56 + s * 4];
        *(floatx4*)&kms[rr * 64 + 4 + 4 * s] = v;
    }
    // km edge zeros: 84 tasks
    if (t < 84) {
        int rr = t / 6, e = t % 6;
        kms[rr * 64 + ((e < 3) ? 1 + e : 57 + e)] = 0.f;
    }
    // x interior: 392 tasks (rr, s, mg) — 4 coalesced float4 loads, pack to 4 b64 writes
    if (t < 392) {
        int rr = t / 28, rem = t % 28, s = rem >> 1, mg = rem & 1;
        int gh = h0 + rr - 3;
        bool valid = ((unsigned)gh < 56u);
        floatx4 f[4];
        #pragma unroll
        for (int mm = 0; mm < 4; mm++) {
            int m = mg * 4 + mm;
            f[mm] = (floatx4){0.f,0.f,0.f,0.f};
            if (valid) f[mm] = *(const floatx4*)&x[((size_t)b * C_ + m * CQ_ + cq) * HW_ + gh * 56 + s * 4];
        }
        #pragma unroll
        for (int u = 0; u < 4; u++) {
            int p = 4 + 4 * s + u;
            unsigned lo = (unsigned)f2bf(f[0][u]) | ((unsigned)f2bf(f[1][u]) << 16);
            unsigned hi = (unsigned)f2bf(f[2][u]) | ((unsigned)f2bf(f[3][u]) << 16);
            unsigned long long pk = (unsigned long long)lo | ((unsigned long long)hi << 32);
            *(unsigned long long*)&xs[(rr * 64 + p) * 8 + mg * 4] = pk;
        }
    }
    // x edge zeros: 168 tasks
    if (t < 168) {
        int rr = t / 12, rem = t % 12, e = rem >> 1, mg = rem & 1;
        int p = (e < 3) ? 1 + e : 57 + e;
        *(unsigned long long*)&xs[(rr * 64 + p) * 8 + mg * 4] = 0ull;
    }
    __syncthreads();

    int r = t / 56, w = t % 56;
    float q = qm[((size_t)b * CQ_ + cq) * HW_ + (h0 + r) * 56 + w];
    const float* gp = gpk + cq * 49;   // wave-uniform -> scalar loads

    float acc[8];
    #pragma unroll
    for (int m = 0; m < 8; m++) acc[m] = 0.f;

    #pragma unroll
    for (int i = 0; i < 7; i++) {
        const float* kr = &kms[(r + i) * 64 + w + 1];
        float v[7], s = 0.f;
        #pragma unroll
        for (int j = 0; j < 7; j++) {   // logits bounded: exp safe without max-sub
            v[j] = __expf(kr[j] * q + gp[i * 7 + j]);
            s += v[j];
        }
        float rm[8];
        #pragma unroll
        for (int m = 0; m < 8; m++) rm[m] = 0.f;
        #pragma unroll
        for (int j = 0; j < 7; j++) {
            short8 xv = *(const short8*)&xs[((r + i) * 64 + w + j + 1) * 8];  // 16B stride: conflict-free
            #pragma unroll
            for (int m = 0; m < 8; m++) rm[m] += v[j] * bf2f(xv[m]);
        }
        float inv = 1.0f / s;
        #pragma unroll
        for (int m = 0; m < 8; m++) acc[m] += inv * rm[m];
    }

    short8 o8;
    #pragma unroll
    for (int m = 0; m < 8; m++) o8[m] = (short)f2bf(acc[m]);
    *(short8*)&pret[((size_t)b * HW_ + (h0 + r) * 56 + w) * C_ + cq * 8] = o8;
}

// ============ K3: final 1x1 conv via MFMA, LDS-free (B-frags direct from pre_t) ============
__global__ void __launch_bounds__(256) fconv_mfma(const short* __restrict__ pret,
                                                  const short* __restrict__ wfp,
                                                  const float* __restrict__ b_f,
                                                  float* __restrict__ out) {
    int hw0 = blockIdx.x * 64;
    int bm  = blockIdx.y;
    int b   = blockIdx.z;
    int t   = threadIdx.x, wave = t >> 6, lane = t & 63, quad = lane >> 4, nl = lane & 15;
    int m0  = bm * 64 + wave * 16;

    const short* arow = wfp + (m0 + nl) * C_ + quad * 8;
    short8 af[8];
    #pragma unroll
    for (int k0 = 0; k0 < 8; k0++) af[k0] = *(const short8*)(arow + k0 * 32);

    floatx4 acc[4];
    #pragma unroll
    for (int nt = 0; nt < 4; nt++) acc[nt] = (floatx4){0.f,0.f,0.f,0.f};

    const short* pb = pret + ((size_t)b * HW_ + hw0 + nl) * C_ + quad * 8;
    #pragma unroll
    for (int nt = 0; nt < 4; nt++) {
        const short* bp = pb + (size_t)nt * 16 * C_;
        #pragma unroll
        for (int k0 = 0; k0 < 8; k0++)
            acc[nt] = __builtin_amdgcn_mfma_f32_16x16x32_bf16(af[k0], *(const short8*)(bp + k0 * 32),
                                                              acc[nt], 0, 0, 0);
    }

    #pragma unroll
    for (int r = 0; r < 4; r++) {
        int ch = m0 + quad * 4 + r;
        float bias = b_f[ch];
        float* dst = out + ((size_t)b * C_ + ch) * HW_ + hw0 + nl;
        #pragma unroll
        for (int nt = 0; nt < 4; nt++)
            dst[nt * 16] = acc[nt][r] + bias;
    }
}

extern "C" void kernel_launch(void* const* d_in, const int* in_sizes, int n_in,
                              void* d_out, int out_size, void* d_ws, size_t ws_size,
                              hipStream_t stream) {
    const float* x    = (const float*)d_in[0];
    const float* w_k  = (const float*)d_in[1];
    const float* b_k  = (const float*)d_in[2];
    const float* w_q  = (const float*)d_in[3];
    const float* b_q  = (const float*)d_in[4];
    const float* w_g1 = (const float*)d_in[5];
    const float* b_g1 = (const float*)d_in[6];
    const float* w_g2 = (const float*)d_in[7];
    const float* b_g2 = (const float*)d_in[8];
    const float* w_f  = (const float*)d_in[9];
    const float* b_f  = (const float*)d_in[10];
    float* out = (float*)d_out;

    float* ws   = (float*)d_ws;
    float* km   = ws;                              // 401408 f32
    float* qm   = km + (size_t)B_ * CQ_ * HW_;     // 401408 f32
    float* gpk  = qm + (size_t)B_ * CQ_ * HW_;     // 1568 f32
    short* wfp  = (short*)(gpk + CQ_ * 49);        // 65536 bf16 (kk-permuted w_f)
    short* pret = wfp + C_ * C_;                   // B*HW*256 bf16, [b][px][kk]

    kq_setup<<<dim3(409), 256, 0, stream>>>(x, w_k, b_k, w_q, b_q, w_f,
                                            w_g1, b_g1, w_g2, b_g2, km, qm, wfp, gpk);
    core_kernel<<<dim3(7, CQ_, B_), 448, 0, stream>>>(x, km, qm, gpk, pret);
    fconv_mfma<<<dim3(HW_ / 64, C_ / 64, B_), 256, 0, stream>>>(pret, wfp, b_f, out);
}